// Round 5
// baseline (480.727 us; speedup 1.0000x reference)
//
#include <hip/hip_runtime.h>
#include <hip/hip_fp16.h>

#define B_ 8
#define S_ 2048
#define D_ 1024
#define M_ (B_ * S_)
#define NCH 16
#define LN_EPS 1e-5f

typedef _Float16 f16;
typedef _Float16 half8 __attribute__((ext_vector_type(8)));
typedef _Float16 half4_t __attribute__((ext_vector_type(4)));
typedef float floatx4 __attribute__((ext_vector_type(4)));

__device__ __forceinline__ void gload_lds16(const void* g, void* l) {
  __builtin_amdgcn_global_load_lds((const __attribute__((address_space(1))) void*)g,
                                   (__attribute__((address_space(3))) void*)l, 16, 0, 0);
}

// T1: bijective XCD-chunk remap (requires total blocks % 8 == 0)
__device__ __forceinline__ void xcd_remap(int& bx, int& by, int& bz) {
  const int gx = gridDim.x, gy = gridDim.y;
  const int nb = gx * gy * (int)gridDim.z;
  int f = blockIdx.x + gx * (blockIdx.y + gy * blockIdx.z);
  const int cpx = nb >> 3;
  f = (f & 7) * cpx + (f >> 3);
  bx = f % gx;
  f /= gx;
  by = f % gy;
  bz = f / gy;
}

// ---------------- fp32 -> fp16 cast (vectorized, grid-stride) ----------------
__global__ void k_cvt(const float* __restrict__ src, f16* __restrict__ dst, int n4) {
  int stride = gridDim.x * blockDim.x;
  for (int i = blockIdx.x * blockDim.x + threadIdx.x; i < n4; i += stride) {
    float4 v = ((const float4*)src)[i];
    half4_t h;
    h.x = (f16)v.x; h.y = (f16)v.y; h.z = (f16)v.z; h.w = (f16)v.w;
    ((half4_t*)dst)[i] = h;
  }
}

// ============ 256x256 8-wave 4-phase GEMM, C = A * B^T (T3+T4+T5) ============
// BK=64, double-buffered LDS (128 KB), counted vmcnt (never 0 in steady state),
// stage order per tile: A0,B0,B1,A1; quadrants (mh,nh): (0,0),(0,1),(1,0),(1,1).
#define STG_A(tn, h, buf)                                                     \
  {                                                                           \
    const f16* g = aG + (size_t)(tn) * 64 + (size_t)(h) * 128 * K;            \
    f16* l = As + (buf) * 16384 + (h) * 8192 + lOff;                          \
    gload_lds16(g, l);                                                        \
    gload_lds16(g + (size_t)64 * K, l + 4096);                                \
  }
#define STG_B(tn, h, buf)                                                     \
  {                                                                           \
    const f16* g = bG + (size_t)(tn) * 64 + (size_t)(h) * 128 * K;            \
    f16* l = Bs + (buf) * 16384 + (h) * 8192 + lOff;                          \
    gload_lds16(g, l);                                                        \
    gload_lds16(g + (size_t)64 * K, l + 4096);                                \
  }

template <bool OUTF16, bool BIAS>
__global__ __launch_bounds__(512, 2) void k_gemm8(
    const f16* __restrict__ A, const f16* __restrict__ Bm, void* __restrict__ Cv,
    const float* __restrict__ bias, const int K, const int N,
    const long sA, const long sB, const long sC) {
  __shared__ f16 As[2 * 256 * 64];
  __shared__ f16 Bs[2 * 256 * 64];
  int bx, by, bz;
  xcd_remap(bx, by, bz);
  const int tid = threadIdx.x;
  const int wid = tid >> 6, lane = tid & 63;
  const int wr = wid >> 2, wc = wid & 3;       // 2 x 4 wave grid
  const int fr = lane & 15, fk = (lane >> 4) * 8;

  const f16* Ab = A + (size_t)bz * sA + (size_t)by * 256 * K;
  const f16* Bb = Bm + (size_t)bz * sB + (size_t)bx * 256 * K;
  const f16* aG = Ab + (size_t)(tid >> 3) * K + (tid & 7) * 8;
  const f16* bG = Bb + (size_t)(tid >> 3) * K + (tid & 7) * 8;
  const int lOff = (tid >> 3) * 64 + (tid & 7) * 8;

  const int NT = K >> 6;

  floatx4 acc[2][4][2][2] = {};

  // prologue: tile 0 -> buf 0 (issue order A0,B0,B1,A1); wait A0,B0; collective
  STG_A(0, 0, 0);
  STG_B(0, 0, 0);
  STG_B(0, 1, 0);
  STG_A(0, 1, 0);
  asm volatile("s_waitcnt vmcnt(4)" ::: "memory");
  __builtin_amdgcn_s_barrier();

  for (int t = 0; t < NT; ++t) {
    const f16* Ac = As + (t & 1) * 16384;
    const f16* Bc = Bs + (t & 1) * 16384;
    const int nb = (t + 1) & 1;
    const bool more = (t + 1 < NT);

#define PHASE(MH, NH, STAGE_STMT, WAIT_STMT)                                  \
    {                                                                         \
      half8 af[4][2], bf[2][2];                                               \
      _Pragma("unroll") for (int m = 0; m < 4; ++m)                           \
        _Pragma("unroll") for (int kk = 0; kk < 2; ++kk)                      \
          af[m][kk] = *(const half8*)(Ac +                                    \
              ((MH) * 128 + wr * 64 + m * 16 + fr) * 64 + kk * 32 + fk);      \
      _Pragma("unroll") for (int n = 0; n < 2; ++n)                           \
        _Pragma("unroll") for (int kk = 0; kk < 2; ++kk)                      \
          bf[n][kk] = *(const half8*)(Bc +                                    \
              ((NH) * 128 + wc * 32 + n * 16 + fr) * 64 + kk * 32 + fk);      \
      STAGE_STMT;                                                             \
      __builtin_amdgcn_s_barrier();                                           \
      __builtin_amdgcn_s_setprio(1);                                          \
      _Pragma("unroll") for (int m = 0; m < 4; ++m)                           \
        _Pragma("unroll") for (int n = 0; n < 2; ++n)                         \
          _Pragma("unroll") for (int kk = 0; kk < 2; ++kk)                    \
            acc[MH][m][NH][n] = __builtin_amdgcn_mfma_f32_16x16x32_f16(       \
                af[m][kk], bf[n][kk], acc[MH][m][NH][n], 0, 0, 0);            \
      __builtin_amdgcn_s_setprio(0);                                          \
      WAIT_STMT;                                                              \
      __builtin_amdgcn_s_barrier();                                           \
    }

    // P1: quad(0,0); stage A0'; end-wait: B1 of tile t
    PHASE(0, 0, if (more) STG_A(t + 1, 0, nb),
          if (more) { asm volatile("s_waitcnt vmcnt(4)" ::: "memory"); }
          else { asm volatile("s_waitcnt vmcnt(2)" ::: "memory"); });
    // P2: quad(0,1) (uses B1); stage B0'; end-wait: A1 of tile t
    PHASE(0, 1, if (more) STG_B(t + 1, 0, nb),
          if (more) { asm volatile("s_waitcnt vmcnt(4)" ::: "memory"); }
          else { asm volatile("s_waitcnt vmcnt(0)" ::: "memory"); });
    // P3: quad(1,0) (uses A1); stage B1'; no wait
    PHASE(1, 0, if (more) STG_B(t + 1, 1, nb), (void)0);
    // P4: quad(1,1); stage A1'; end-wait: A0',B0' of tile t+1
    PHASE(1, 1, if (more) STG_A(t + 1, 1, nb),
          if (more) { asm volatile("s_waitcnt vmcnt(4)" ::: "memory"); });
#undef PHASE
  }

  // epilogue: C/D layout col=lane&15, row=(lane>>4)*4+reg
#pragma unroll
  for (int mh = 0; mh < 2; ++mh)
#pragma unroll
    for (int m = 0; m < 4; ++m) {
      const int row0 = by * 256 + mh * 128 + wr * 64 + m * 16 + (lane >> 4) * 4;
#pragma unroll
      for (int nh = 0; nh < 2; ++nh)
#pragma unroll
        for (int n = 0; n < 2; ++n) {
          const int col = bx * 256 + nh * 128 + wc * 32 + n * 16 + (lane & 15);
          float bv = 0.0f;
          if constexpr (BIAS) bv = bias[col];
#pragma unroll
          for (int r = 0; r < 4; ++r) {
            const float v = acc[mh][m][nh][n][r] + bv;
            if constexpr (OUTF16)
              ((f16*)Cv)[(size_t)bz * sC + (size_t)(row0 + r) * N + col] = (f16)v;
            else
              ((float*)Cv)[(size_t)bz * sC + (size_t)(row0 + r) * N + col] = v;
          }
        }
    }
}

// -------- scores GEMM: Sc = Q*K^T (f16 out) + fused per-tile column stats ----
// (proven 128^2 m97-structure; migrates to 8-phase next round)
__global__ __launch_bounds__(256) void k_scores(
    const f16* __restrict__ Q, const f16* __restrict__ Kx, f16* __restrict__ Sc,
    float* __restrict__ pm, float* __restrict__ pz) {
  __shared__ f16 As[128 * 32];
  __shared__ f16 Bs[128 * 32];
  __shared__ float smax[2][128];
  __shared__ float ssum[2][128];
  int bx, by, bz;
  xcd_remap(bx, by, bz);
  const int tid = threadIdx.x;
  const int wid = tid >> 6, lane = tid & 63;
  const int wr = wid >> 1, wc = wid & 1;

  const f16* Ab = Q + (size_t)bz * S_ * D_ + (size_t)by * 128 * D_;
  const f16* Bb = Kx + (size_t)bz * S_ * D_ + (size_t)bx * 128 * D_;

  const int srow = wid * 32 + (lane >> 2);
  const int scol = (lane & 3) * 8;
  const f16* a_src0 = Ab + (size_t)srow * D_ + scol;
  const f16* a_src1 = a_src0 + (size_t)16 * D_;
  const f16* b_src0 = Bb + (size_t)srow * D_ + scol;
  const f16* b_src1 = b_src0 + (size_t)16 * D_;
  f16* a_dst0 = As + wid * 1024;
  f16* a_dst1 = a_dst0 + 512;
  f16* b_dst0 = Bs + wid * 1024;
  f16* b_dst1 = b_dst0 + 512;

  const int fr = lane & 15, fk = (lane >> 4) * 8;
  const f16* a_f = As + (wr * 64 + fr) * 32 + fk;
  const f16* b_f = Bs + (wc * 64 + fr) * 32 + fk;

  floatx4 acc[4][4] = {};

  for (int k0 = 0; k0 < D_; k0 += 32) {
    gload_lds16(a_src0 + k0, a_dst0);
    gload_lds16(a_src1 + k0, a_dst1);
    gload_lds16(b_src0 + k0, b_dst0);
    gload_lds16(b_src1 + k0, b_dst1);
    __syncthreads();
    half8 af[4], bf[4];
#pragma unroll
    for (int m = 0; m < 4; ++m) af[m] = *(const half8*)(a_f + m * 16 * 32);
#pragma unroll
    for (int n = 0; n < 4; ++n) bf[n] = *(const half8*)(b_f + n * 16 * 32);
#pragma unroll
    for (int m = 0; m < 4; ++m)
#pragma unroll
      for (int n = 0; n < 4; ++n)
        acc[m][n] = __builtin_amdgcn_mfma_f32_16x16x32_f16(af[m], bf[n], acc[m][n], 0, 0, 0);
    __syncthreads();
  }

  const int crow0 = by * 128 + wr * 64 + (lane >> 4) * 4;
  const int ccol0 = bx * 128 + wc * 64 + (lane & 15);
#pragma unroll
  for (int n = 0; n < 4; ++n)
#pragma unroll
    for (int m = 0; m < 4; ++m)
#pragma unroll
      for (int r = 0; r < 4; ++r)
        Sc[(size_t)bz * S_ * S_ + (size_t)(crow0 + m * 16 + r) * S_ + ccol0 + n * 16] =
            (f16)acc[m][n][r];

  float cmax[4], csum[4];
#pragma unroll
  for (int n = 0; n < 4; ++n) {
    float mx = -1e30f;
#pragma unroll
    for (int m = 0; m < 4; ++m)
#pragma unroll
      for (int r = 0; r < 4; ++r) mx = fmaxf(mx, (float)(f16)acc[m][n][r]);
    float zz = 0.f;
#pragma unroll
    for (int m = 0; m < 4; ++m)
#pragma unroll
      for (int r = 0; r < 4; ++r) zz += __expf((float)(f16)acc[m][n][r] - mx);
#pragma unroll
    for (int o = 16; o <= 32; o <<= 1) {
      const float om = __shfl_xor(mx, o);
      const float oz = __shfl_xor(zz, o);
      const float nm = fmaxf(mx, om);
      zz = zz * __expf(mx - nm) + oz * __expf(om - nm);
      mx = nm;
    }
    cmax[n] = mx;
    csum[n] = zz;
  }
  __syncthreads();
  if ((lane >> 4) == 0) {
#pragma unroll
    for (int n = 0; n < 4; ++n) {
      const int c = wc * 64 + n * 16 + lane;
      smax[wr][c] = cmax[n];
      ssum[wr][c] = csum[n];
    }
  }
  __syncthreads();
  if (wr == 0 && lane < 16) {
#pragma unroll
    for (int n = 0; n < 4; ++n) {
      const int c = wc * 64 + n * 16 + lane;
      const float m0 = smax[0][c], m1 = smax[1][c];
      const float nm = fmaxf(m0, m1);
      const float zz = ssum[0][c] * __expf(m0 - nm) + ssum[1][c] * __expf(m1 - nm);
      const size_t o = ((size_t)bz * NCH + by) * S_ + bx * 128 + c;
      pm[o] = nm;
      pz[o] = zz;
    }
  }
}

__global__ void k_combine(const float* __restrict__ pm, const float* __restrict__ pz,
                          float* __restrict__ mcol, float* __restrict__ cscale) {
  const int b = blockIdx.y;
  const int j = blockIdx.x * 256 + threadIdx.x;
  float m = -1e30f;
#pragma unroll
  for (int ch = 0; ch < NCH; ++ch) m = fmaxf(m, pm[((size_t)b * NCH + ch) * S_ + j]);
  float z = 0.f;
#pragma unroll
  for (int ch = 0; ch < NCH; ++ch)
    z += pz[((size_t)b * NCH + ch) * S_ + j] * __expf(pm[((size_t)b * NCH + ch) * S_ + j] - m);
  mcol[(size_t)b * S_ + j] = m;
  cscale[(size_t)b * S_ + j] = 1.0f / (z * 32.0f);  // fold /sqrt(D), D=1024
}

// ------------- in-place P[z][i][j] = exp(s - m_j) * cscale_j  (f16) ----------
__global__ void k_pexp16(f16* __restrict__ P, const float* __restrict__ mcol,
                         const float* __restrict__ cscale) {
  const int n4 = B_ * S_ * S_ / 4;
  const int stride = gridDim.x * blockDim.x;
  for (int i = blockIdx.x * blockDim.x + threadIdx.x; i < n4; i += stride) {
    const size_t e = (size_t)i * 4;
    const int z = (int)(e / ((size_t)S_ * S_));
    const int j = (int)(e & (S_ - 1));
    const half4_t s4 = ((const half4_t*)P)[i];
    const float4 mv = *(const float4*)(mcol + (size_t)z * S_ + j);
    const float4 cv = *(const float4*)(cscale + (size_t)z * S_ + j);
    half4_t h;
    h.x = (f16)(__expf((float)s4.x - mv.x) * cv.x);
    h.y = (f16)(__expf((float)s4.y - mv.y) * cv.y);
    h.z = (f16)(__expf((float)s4.z - mv.z) * cv.z);
    h.w = (f16)(__expf((float)s4.w - mv.w) * cv.w);
    ((half4_t*)P)[i] = h;
  }
}

// ---------------- V[z*S+...][D] -> Vt[z][D][S] tiled transpose ----------------
__global__ void k_transpose(const f16* __restrict__ V, f16* __restrict__ Vt) {
  __shared__ f16 t[64][72];
  const int b = blockIdx.z;
  const int j0 = blockIdx.x * 64, d0 = blockIdx.y * 64;
  const int rr = threadIdx.x >> 4;
  const int cc = (threadIdx.x & 15) * 4;
#pragma unroll
  for (int p = 0; p < 4; ++p) {
    const int j = rr + p * 16;
    const half4_t v = *(const half4_t*)(V + ((size_t)b * S_ + j0 + j) * D_ + d0 + cc);
    *(half4_t*)&t[j][cc] = v;
  }
  __syncthreads();
#pragma unroll
  for (int p = 0; p < 4; ++p) {
    const int d = rr + p * 16;
    half4_t v;
    v.x = t[cc][d]; v.y = t[cc + 1][d]; v.z = t[cc + 2][d]; v.w = t[cc + 3][d];
    *(half4_t*)(Vt + ((size_t)b * D_ + d0 + d) * S_ + j0 + cc) = v;
  }
}

// ------------- LayerNorm per row + partial mean-pool (deterministic) ---------
__global__ __launch_bounds__(256) void k_ln_pool(
    const f16* __restrict__ selfatt, const float* __restrict__ gamma,
    const float* __restrict__ beta, float* __restrict__ part) {
  __shared__ float lds[4 * 1024];
  const int tid = threadIdx.x, wid = tid >> 6, lane = tid & 63;
  const int row0 = blockIdx.x * 64 + wid * 16;
  float g[16], be[16], acc[16];
#pragma unroll
  for (int t = 0; t < 16; ++t) {
    g[t] = gamma[lane + 64 * t];
    be[t] = beta[lane + 64 * t];
    acc[t] = 0.f;
  }
  for (int r = 0; r < 16; ++r) {
    const f16* xp = selfatt + (size_t)(row0 + r) * D_ + lane;
    float x[16], sum = 0.f, sq = 0.f;
#pragma unroll
    for (int t = 0; t < 16; ++t) {
      x[t] = (float)xp[64 * t];
      sum += x[t];
      sq += x[t] * x[t];
    }
#pragma unroll
    for (int o = 32; o > 0; o >>= 1) {
      sum += __shfl_xor(sum, o);
      sq += __shfl_xor(sq, o);
    }
    const float mu = sum * (1.f / 1024.f);
    const float var = sq * (1.f / 1024.f) - mu * mu;
    const float rstd = rsqrtf(var + LN_EPS);
#pragma unroll
    for (int t = 0; t < 16; ++t) acc[t] += (x[t] - mu) * rstd * g[t] + be[t];
  }
#pragma unroll
  for (int t = 0; t < 16; ++t) lds[wid * 1024 + lane + 64 * t] = acc[t];
  __syncthreads();
#pragma unroll
  for (int c = 0; c < 4; ++c) {
    const int d = tid + 256 * c;
    const float s = lds[d] + lds[1024 + d] + lds[2048 + d] + lds[3072 + d];
    part[(size_t)blockIdx.x * 1024 + d] = s;
  }
}

__global__ void k_final(const float* __restrict__ part, float* __restrict__ out) {
  const int idx = blockIdx.x * 256 + threadIdx.x;
  const int b = idx >> 10, d = idx & 1023;
  float s = 0.f;
#pragma unroll
  for (int slot = 0; slot < 32; ++slot)
    s += part[((size_t)(b * 32 + slot)) * 1024 + d];
  out[idx] = s * (1.0f / S_);
}

// ---------------------------------------------------------------------------
extern "C" void kernel_launch(void* const* d_in, const int* in_sizes, int n_in,
                              void* d_out, int out_size, void* d_ws, size_t ws_size,
                              hipStream_t stream) {
  (void)in_sizes; (void)n_in; (void)out_size;
  const float* inp = (const float*)d_in[0];
  const float* Wq = (const float*)d_in[2];
  const float* bq = (const float*)d_in[3];
  const float* Wk = (const float*)d_in[4];
  const float* bk = (const float*)d_in[5];
  const float* Wv = (const float*)d_in[6];
  const float* bv = (const float*)d_in[7];
  const float* gamma = (const float*)d_in[8];
  const float* beta = (const float*)d_in[9];
  float* out = (float*)d_out;

  char* ws = (char*)d_ws;
  const size_t MB = 1024 * 1024;
  if (ws_size < 244 * MB) return;  // proven available in round 3

  f16* Xh = (f16*)(ws);                   // [0,32) X -> selfatt
  f16* Qh = (f16*)(ws + 32 * MB);         // [32,64)
  f16* Kh = (f16*)(ws + 64 * MB);         // [64,96)
  f16* Vh = (f16*)(ws + 96 * MB);         // [96,128) dead after transpose
  f16* Vt = (f16*)(ws + 128 * MB);        // [128,160) [B][D][S]
  f16* Sc = (f16*)(ws + 160 * MB);        // [160,224) [B][S][S] f16 scores -> P
  f16* Wh = (f16*)(ws + 224 * MB);        // [224,230) [3][D][D]
  float* pm = (float*)(ws + 230 * MB);    // 1 MB [B][NCH][S]
  float* pz = (float*)(ws + 231 * MB);    // 1 MB
  float* mcol = (float*)(ws + 232 * MB);  // 64 KB [B][S]
  float* cscale = mcol + (size_t)B_ * S_; // 64 KB
  float* part = (float*)(ws + 233 * MB);  // 1 MB [256][1024]
  f16* selfatt = Xh;

  k_cvt<<<2048, 256, 0, stream>>>(inp, Xh, M_ * D_ / 4);
  k_cvt<<<512, 256, 0, stream>>>(Wq, Wh, D_ * D_ / 4);
  k_cvt<<<512, 256, 0, stream>>>(Wk, Wh + D_ * D_, D_ * D_ / 4);
  k_cvt<<<512, 256, 0, stream>>>(Wv, Wh + 2 * D_ * D_, D_ * D_ / 4);

  // projections: 256^2 8-phase GEMM (K=1024)
  dim3 gp8(D_ / 256, M_ / 256, 1);
  k_gemm8<true, true><<<gp8, 512, 0, stream>>>(Xh, Wh, Qh, bq, D_, D_, 0, 0, 0);
  k_gemm8<true, true><<<gp8, 512, 0, stream>>>(Xh, Wh + D_ * D_, Kh, bk, D_, D_, 0, 0, 0);
  k_gemm8<true, true><<<gp8, 512, 0, stream>>>(Xh, Wh + 2 * D_ * D_, Vh, bv, D_, D_, 0, 0, 0);

  k_transpose<<<dim3(S_ / 64, D_ / 64, B_), 256, 0, stream>>>(Vh, Vt);

  k_scores<<<dim3(S_ / 128, S_ / 128, B_), 256, 0, stream>>>(Qh, Kh, Sc, pm, pz);
  k_combine<<<dim3(S_ / 256, B_), 256, 0, stream>>>(pm, pz, mcol, cscale);
  k_pexp16<<<2048, 256, 0, stream>>>(Sc, mcol, cscale);

  // PV: selfatt = P * (Vt)^T over all 8 batches, 256^2 8-phase (K=2048)
  k_gemm8<true, false><<<dim3(D_ / 256, S_ / 256, B_), 512, 0, stream>>>(
      Sc, Vt, selfatt, nullptr, S_, D_,
      (long)S_ * S_, (long)D_ * S_, (long)S_ * D_);

  k_ln_pool<<<M_ / 64, 256, 0, stream>>>(selfatt, gamma, beta, part);
  k_final<<<(B_ * D_) / 256, 256, 0, stream>>>(part, out);
}

// Round 6
// 366.391 us; speedup vs baseline: 1.3121x; 1.3121x over previous
//
#include <hip/hip_runtime.h>
#include <hip/hip_fp16.h>

#define B_ 8
#define S_ 2048
#define D_ 1024
#define M_ (B_ * S_)
#define NCH 16
#define LN_EPS 1e-5f

typedef _Float16 f16;
typedef _Float16 half8 __attribute__((ext_vector_type(8)));
typedef _Float16 half4_t __attribute__((ext_vector_type(4)));
typedef float floatx4 __attribute__((ext_vector_type(4)));

__device__ __forceinline__ void gload_lds16(const void* g, void* l) {
  __builtin_amdgcn_global_load_lds((const __attribute__((address_space(1))) void*)g,
                                   (__attribute__((address_space(3))) void*)l, 16, 0, 0);
}

// T1: bijective XCD-chunk remap (requires total blocks % 8 == 0)
__device__ __forceinline__ void xcd_remap(int& bx, int& by, int& bz) {
  const int gx = gridDim.x, gy = gridDim.y;
  const int nb = gx * gy * (int)gridDim.z;
  int f = blockIdx.x + gx * (blockIdx.y + gy * blockIdx.z);
  const int cpx = nb >> 3;
  f = (f & 7) * cpx + (f >> 3);
  bx = f % gx;
  f /= gx;
  by = f % gy;
  bz = f / gy;
}

// ---------------- fp32 -> fp16 cast (vectorized, grid-stride) ----------------
__global__ void k_cvt(const float* __restrict__ src, f16* __restrict__ dst, int n4) {
  int stride = gridDim.x * blockDim.x;
  for (int i = blockIdx.x * blockDim.x + threadIdx.x; i < n4; i += stride) {
    float4 v = ((const float4*)src)[i];
    half4_t h;
    h.x = (f16)v.x; h.y = (f16)v.y; h.z = (f16)v.z; h.w = (f16)v.w;
    ((half4_t*)dst)[i] = h;
  }
}

// ============ 256x256 8-wave 4-phase GEMM, C = A * B^T (T2+T3+T4+T5) =========
// BK=64, double-buffered LDS (128 KB), counted vmcnt (never 0 in steady state).
// T2: 16B-slot XOR swizzle, physical_slot = logical_slot ^ (row & 7).
//     LDS writes stay LINEAR (global_load_lds); the global SOURCE column is
//     pre-swizzled, reads apply the same XOR (involution => exact inverse).
#define STG_A(tn, h, buf)                                                     \
  {                                                                           \
    const f16* g = aG + (size_t)(tn) * 64 + (size_t)(h) * 128 * K;            \
    f16* l = As + (buf) * 16384 + (h) * 8192 + lOff;                          \
    gload_lds16(g, l);                                                        \
    gload_lds16(g + (size_t)64 * K, l + 4096);                                \
  }
#define STG_B(tn, h, buf)                                                     \
  {                                                                           \
    const f16* g = bG + (size_t)(tn) * 64 + (size_t)(h) * 128 * K;            \
    f16* l = Bs + (buf) * 16384 + (h) * 8192 + lOff;                          \
    gload_lds16(g, l);                                                        \
    gload_lds16(g + (size_t)64 * K, l + 4096);                                \
  }

template <bool OUTF16, bool BIAS>
__global__ __launch_bounds__(512, 2) void k_gemm8(
    const f16* __restrict__ A, const f16* __restrict__ Bm, void* __restrict__ Cv,
    const float* __restrict__ bias, const int K, const int N,
    const long sA, const long sB, const long sC) {
  __shared__ f16 As[2 * 256 * 64];
  __shared__ f16 Bs[2 * 256 * 64];
  int bx, by, bz;
  xcd_remap(bx, by, bz);
  const int tid = threadIdx.x;
  const int wid = tid >> 6, lane = tid & 63;
  const int wr = wid >> 2, wc = wid & 3;       // 2 x 4 wave grid
  const int fr = lane & 15;

  const f16* Ab = A + (size_t)bz * sA + (size_t)by * 256 * K;
  const f16* Bb = Bm + (size_t)bz * sB + (size_t)bx * 256 * K;
  // T2: pre-swizzled source column slot; (row+64)&7 == row&7 so one form works
  const int srow = tid >> 3;
  const int sslot = (tid & 7) ^ (srow & 7);
  const f16* aG = Ab + (size_t)srow * K + sslot * 8;
  const f16* bG = Bb + (size_t)srow * K + sslot * 8;
  const int lOff = srow * 64 + (tid & 7) * 8;  // linear LDS dest

  // T2 read-side: physical slot offsets (elements) for kk=0/1
  const int sx = lane & 7;
  const int fs0 = (((lane >> 4)) ^ sx) * 8;
  const int fs1 = ((4 + (lane >> 4)) ^ sx) * 8;

  const int NT = K >> 6;

  floatx4 acc[2][4][2][2] = {};

  // prologue: tile 0 -> buf 0 (issue order A0,B0,B1,A1); wait A0,B0
  STG_A(0, 0, 0);
  STG_B(0, 0, 0);
  STG_B(0, 1, 0);
  STG_A(0, 1, 0);
  asm volatile("s_waitcnt vmcnt(4)" ::: "memory");
  __builtin_amdgcn_s_barrier();

  for (int t = 0; t < NT; ++t) {
    const f16* Ac = As + (t & 1) * 16384;
    const f16* Bc = Bs + (t & 1) * 16384;
    const int nb = (t + 1) & 1;
    const bool more = (t + 1 < NT);

#define PHASE(MH, NH, STAGE_STMT, WAIT_STMT)                                  \
    {                                                                         \
      half8 af[4][2], bf[2][2];                                               \
      _Pragma("unroll") for (int m = 0; m < 4; ++m) {                         \
        const int ar = ((MH) * 128 + wr * 64 + m * 16 + fr) * 64;             \
        af[m][0] = *(const half8*)(Ac + ar + fs0);                            \
        af[m][1] = *(const half8*)(Ac + ar + fs1);                            \
      }                                                                       \
      _Pragma("unroll") for (int n = 0; n < 2; ++n) {                         \
        const int br = ((NH) * 128 + wc * 32 + n * 16 + fr) * 64;             \
        bf[n][0] = *(const half8*)(Bc + br + fs0);                            \
        bf[n][1] = *(const half8*)(Bc + br + fs1);                            \
      }                                                                       \
      STAGE_STMT;                                                             \
      __builtin_amdgcn_s_barrier();                                           \
      __builtin_amdgcn_s_setprio(1);                                          \
      _Pragma("unroll") for (int m = 0; m < 4; ++m)                           \
        _Pragma("unroll") for (int n = 0; n < 2; ++n)                         \
          _Pragma("unroll") for (int kk = 0; kk < 2; ++kk)                    \
            acc[MH][m][NH][n] = __builtin_amdgcn_mfma_f32_16x16x32_f16(       \
                af[m][kk], bf[n][kk], acc[MH][m][NH][n], 0, 0, 0);            \
      __builtin_amdgcn_s_setprio(0);                                          \
      WAIT_STMT;                                                              \
      __builtin_amdgcn_s_barrier();                                           \
    }

    // P1: quad(0,0); stage A0'; end-wait: B1 of tile t
    PHASE(0, 0, if (more) STG_A(t + 1, 0, nb),
          if (more) { asm volatile("s_waitcnt vmcnt(4)" ::: "memory"); }
          else { asm volatile("s_waitcnt vmcnt(2)" ::: "memory"); });
    // P2: quad(0,1) (uses B1); stage B0'; end-wait: A1 of tile t
    PHASE(0, 1, if (more) STG_B(t + 1, 0, nb),
          if (more) { asm volatile("s_waitcnt vmcnt(4)" ::: "memory"); }
          else { asm volatile("s_waitcnt vmcnt(0)" ::: "memory"); });
    // P3: quad(1,0) (uses A1); stage B1'; no wait
    PHASE(1, 0, if (more) STG_B(t + 1, 1, nb), (void)0);
    // P4: quad(1,1); stage A1'; end-wait: A0',B0' of tile t+1
    PHASE(1, 1, if (more) STG_A(t + 1, 1, nb),
          if (more) { asm volatile("s_waitcnt vmcnt(4)" ::: "memory"); });
#undef PHASE
  }

  // epilogue: C/D layout col=lane&15, row=(lane>>4)*4+reg
#pragma unroll
  for (int mh = 0; mh < 2; ++mh)
#pragma unroll
    for (int m = 0; m < 4; ++m) {
      const int row0 = by * 256 + mh * 128 + wr * 64 + m * 16 + (lane >> 4) * 4;
#pragma unroll
      for (int nh = 0; nh < 2; ++nh)
#pragma unroll
        for (int n = 0; n < 2; ++n) {
          const int col = bx * 256 + nh * 128 + wc * 32 + n * 16 + (lane & 15);
          float bv = 0.0f;
          if constexpr (BIAS) bv = bias[col];
#pragma unroll
          for (int r = 0; r < 4; ++r) {
            const float v = acc[mh][m][nh][n][r] + bv;
            if constexpr (OUTF16)
              ((f16*)Cv)[(size_t)bz * sC + (size_t)(row0 + r) * N + col] = (f16)v;
            else
              ((float*)Cv)[(size_t)bz * sC + (size_t)(row0 + r) * N + col] = v;
          }
        }
    }
}

// -------- scores GEMM: Sc = Q*K^T (f16 out) + fused per-tile column stats ----
// (proven 128^2 m97-structure; migrates to 8-phase once swizzle verified)
__global__ __launch_bounds__(256) void k_scores(
    const f16* __restrict__ Q, const f16* __restrict__ Kx, f16* __restrict__ Sc,
    float* __restrict__ pm, float* __restrict__ pz) {
  __shared__ f16 As[128 * 32];
  __shared__ f16 Bs[128 * 32];
  __shared__ float smax[2][128];
  __shared__ float ssum[2][128];
  int bx, by, bz;
  xcd_remap(bx, by, bz);
  const int tid = threadIdx.x;
  const int wid = tid >> 6, lane = tid & 63;
  const int wr = wid >> 1, wc = wid & 1;

  const f16* Ab = Q + (size_t)bz * S_ * D_ + (size_t)by * 128 * D_;
  const f16* Bb = Kx + (size_t)bz * S_ * D_ + (size_t)bx * 128 * D_;

  const int srow = wid * 32 + (lane >> 2);
  const int scol = (lane & 3) * 8;
  const f16* a_src0 = Ab + (size_t)srow * D_ + scol;
  const f16* a_src1 = a_src0 + (size_t)16 * D_;
  const f16* b_src0 = Bb + (size_t)srow * D_ + scol;
  const f16* b_src1 = b_src0 + (size_t)16 * D_;
  f16* a_dst0 = As + wid * 1024;
  f16* a_dst1 = a_dst0 + 512;
  f16* b_dst0 = Bs + wid * 1024;
  f16* b_dst1 = b_dst0 + 512;

  const int fr = lane & 15, fk = (lane >> 4) * 8;
  const f16* a_f = As + (wr * 64 + fr) * 32 + fk;
  const f16* b_f = Bs + (wc * 64 + fr) * 32 + fk;

  floatx4 acc[4][4] = {};

  for (int k0 = 0; k0 < D_; k0 += 32) {
    gload_lds16(a_src0 + k0, a_dst0);
    gload_lds16(a_src1 + k0, a_dst1);
    gload_lds16(b_src0 + k0, b_dst0);
    gload_lds16(b_src1 + k0, b_dst1);
    __syncthreads();
    half8 af[4], bf[4];
#pragma unroll
    for (int m = 0; m < 4; ++m) af[m] = *(const half8*)(a_f + m * 16 * 32);
#pragma unroll
    for (int n = 0; n < 4; ++n) bf[n] = *(const half8*)(b_f + n * 16 * 32);
#pragma unroll
    for (int m = 0; m < 4; ++m)
#pragma unroll
      for (int n = 0; n < 4; ++n)
        acc[m][n] = __builtin_amdgcn_mfma_f32_16x16x32_f16(af[m], bf[n], acc[m][n], 0, 0, 0);
    __syncthreads();
  }

  const int crow0 = by * 128 + wr * 64 + (lane >> 4) * 4;
  const int ccol0 = bx * 128 + wc * 64 + (lane & 15);
#pragma unroll
  for (int n = 0; n < 4; ++n)
#pragma unroll
    for (int m = 0; m < 4; ++m)
#pragma unroll
      for (int r = 0; r < 4; ++r)
        Sc[(size_t)bz * S_ * S_ + (size_t)(crow0 + m * 16 + r) * S_ + ccol0 + n * 16] =
            (f16)acc[m][n][r];

  float cmax[4], csum[4];
#pragma unroll
  for (int n = 0; n < 4; ++n) {
    float mx = -1e30f;
#pragma unroll
    for (int m = 0; m < 4; ++m)
#pragma unroll
      for (int r = 0; r < 4; ++r) mx = fmaxf(mx, (float)(f16)acc[m][n][r]);
    float zz = 0.f;
#pragma unroll
    for (int m = 0; m < 4; ++m)
#pragma unroll
      for (int r = 0; r < 4; ++r) zz += __expf((float)(f16)acc[m][n][r] - mx);
#pragma unroll
    for (int o = 16; o <= 32; o <<= 1) {
      const float om = __shfl_xor(mx, o);
      const float oz = __shfl_xor(zz, o);
      const float nm = fmaxf(mx, om);
      zz = zz * __expf(mx - nm) + oz * __expf(om - nm);
      mx = nm;
    }
    cmax[n] = mx;
    csum[n] = zz;
  }
  __syncthreads();
  if ((lane >> 4) == 0) {
#pragma unroll
    for (int n = 0; n < 4; ++n) {
      const int c = wc * 64 + n * 16 + lane;
      smax[wr][c] = cmax[n];
      ssum[wr][c] = csum[n];
    }
  }
  __syncthreads();
  if (wr == 0 && lane < 16) {
#pragma unroll
    for (int n = 0; n < 4; ++n) {
      const int c = wc * 64 + n * 16 + lane;
      const float m0 = smax[0][c], m1 = smax[1][c];
      const float nm = fmaxf(m0, m1);
      const float zz = ssum[0][c] * __expf(m0 - nm) + ssum[1][c] * __expf(m1 - nm);
      const size_t o = ((size_t)bz * NCH + by) * S_ + bx * 128 + c;
      pm[o] = nm;
      pz[o] = zz;
    }
  }
}

__global__ void k_combine(const float* __restrict__ pm, const float* __restrict__ pz,
                          float* __restrict__ mcol, float* __restrict__ cscale) {
  const int b = blockIdx.y;
  const int j = blockIdx.x * 256 + threadIdx.x;
  float m = -1e30f;
#pragma unroll
  for (int ch = 0; ch < NCH; ++ch) m = fmaxf(m, pm[((size_t)b * NCH + ch) * S_ + j]);
  float z = 0.f;
#pragma unroll
  for (int ch = 0; ch < NCH; ++ch)
    z += pz[((size_t)b * NCH + ch) * S_ + j] * __expf(pm[((size_t)b * NCH + ch) * S_ + j] - m);
  mcol[(size_t)b * S_ + j] = m;
  cscale[(size_t)b * S_ + j] = 1.0f / (z * 32.0f);  // fold /sqrt(D), D=1024
}

// ------------- in-place P[z][i][j] = exp(s - m_j) * cscale_j  (f16) ----------
__global__ void k_pexp16(f16* __restrict__ P, const float* __restrict__ mcol,
                         const float* __restrict__ cscale) {
  const int n4 = B_ * S_ * S_ / 4;
  const int stride = gridDim.x * blockDim.x;
  for (int i = blockIdx.x * blockDim.x + threadIdx.x; i < n4; i += stride) {
    const size_t e = (size_t)i * 4;
    const int z = (int)(e / ((size_t)S_ * S_));
    const int j = (int)(e & (S_ - 1));
    const half4_t s4 = ((const half4_t*)P)[i];
    const float4 mv = *(const float4*)(mcol + (size_t)z * S_ + j);
    const float4 cv = *(const float4*)(cscale + (size_t)z * S_ + j);
    half4_t h;
    h.x = (f16)(__expf((float)s4.x - mv.x) * cv.x);
    h.y = (f16)(__expf((float)s4.y - mv.y) * cv.y);
    h.z = (f16)(__expf((float)s4.z - mv.z) * cv.z);
    h.w = (f16)(__expf((float)s4.w - mv.w) * cv.w);
    ((half4_t*)P)[i] = h;
  }
}

// ---------------- V[z*S+...][D] -> Vt[z][D][S] tiled transpose ----------------
__global__ void k_transpose(const f16* __restrict__ V, f16* __restrict__ Vt) {
  __shared__ f16 t[64][72];
  const int b = blockIdx.z;
  const int j0 = blockIdx.x * 64, d0 = blockIdx.y * 64;
  const int rr = threadIdx.x >> 4;
  const int cc = (threadIdx.x & 15) * 4;
#pragma unroll
  for (int p = 0; p < 4; ++p) {
    const int j = rr + p * 16;
    const half4_t v = *(const half4_t*)(V + ((size_t)b * S_ + j0 + j) * D_ + d0 + cc);
    *(half4_t*)&t[j][cc] = v;
  }
  __syncthreads();
#pragma unroll
  for (int p = 0; p < 4; ++p) {
    const int d = rr + p * 16;
    half4_t v;
    v.x = t[cc][d]; v.y = t[cc + 1][d]; v.z = t[cc + 2][d]; v.w = t[cc + 3][d];
    *(half4_t*)(Vt + ((size_t)b * D_ + d0 + d) * S_ + j0 + cc) = v;
  }
}

// ------------- LayerNorm per row + partial mean-pool (deterministic) ---------
__global__ __launch_bounds__(256) void k_ln_pool(
    const f16* __restrict__ selfatt, const float* __restrict__ gamma,
    const float* __restrict__ beta, float* __restrict__ part) {
  __shared__ float lds[4 * 1024];
  const int tid = threadIdx.x, wid = tid >> 6, lane = tid & 63;
  const int row0 = blockIdx.x * 64 + wid * 16;
  float g[16], be[16], acc[16];
#pragma unroll
  for (int t = 0; t < 16; ++t) {
    g[t] = gamma[lane + 64 * t];
    be[t] = beta[lane + 64 * t];
    acc[t] = 0.f;
  }
  for (int r = 0; r < 16; ++r) {
    const f16* xp = selfatt + (size_t)(row0 + r) * D_ + lane;
    float x[16], sum = 0.f, sq = 0.f;
#pragma unroll
    for (int t = 0; t < 16; ++t) {
      x[t] = (float)xp[64 * t];
      sum += x[t];
      sq += x[t] * x[t];
    }
#pragma unroll
    for (int o = 32; o > 0; o >>= 1) {
      sum += __shfl_xor(sum, o);
      sq += __shfl_xor(sq, o);
    }
    const float mu = sum * (1.f / 1024.f);
    const float var = sq * (1.f / 1024.f) - mu * mu;
    const float rstd = rsqrtf(var + LN_EPS);
#pragma unroll
    for (int t = 0; t < 16; ++t) acc[t] += (x[t] - mu) * rstd * g[t] + be[t];
  }
#pragma unroll
  for (int t = 0; t < 16; ++t) lds[wid * 1024 + lane + 64 * t] = acc[t];
  __syncthreads();
#pragma unroll
  for (int c = 0; c < 4; ++c) {
    const int d = tid + 256 * c;
    const float s = lds[d] + lds[1024 + d] + lds[2048 + d] + lds[3072 + d];
    part[(size_t)blockIdx.x * 1024 + d] = s;
  }
}

__global__ void k_final(const float* __restrict__ part, float* __restrict__ out) {
  const int idx = blockIdx.x * 256 + threadIdx.x;
  const int b = idx >> 10, d = idx & 1023;
  float s = 0.f;
#pragma unroll
  for (int slot = 0; slot < 32; ++slot)
    s += part[((size_t)(b * 32 + slot)) * 1024 + d];
  out[idx] = s * (1.0f / S_);
}

// ---------------------------------------------------------------------------
extern "C" void kernel_launch(void* const* d_in, const int* in_sizes, int n_in,
                              void* d_out, int out_size, void* d_ws, size_t ws_size,
                              hipStream_t stream) {
  (void)in_sizes; (void)n_in; (void)out_size;
  const float* inp = (const float*)d_in[0];
  const float* Wq = (const float*)d_in[2];
  const float* bq = (const float*)d_in[3];
  const float* Wk = (const float*)d_in[4];
  const float* bk = (const float*)d_in[5];
  const float* Wv = (const float*)d_in[6];
  const float* bv = (const float*)d_in[7];
  const float* gamma = (const float*)d_in[8];
  const float* beta = (const float*)d_in[9];
  float* out = (float*)d_out;

  char* ws = (char*)d_ws;
  const size_t MB = 1024 * 1024;
  if (ws_size < 244 * MB) return;  // proven available in round 3

  f16* Xh = (f16*)(ws);                   // [0,32) X -> selfatt
  f16* Qh = (f16*)(ws + 32 * MB);         // [32,64)
  f16* Kh = (f16*)(ws + 64 * MB);         // [64,96)
  f16* Vh = (f16*)(ws + 96 * MB);         // [96,128) dead after transpose
  f16* Vt = (f16*)(ws + 128 * MB);        // [128,160) [B][D][S]
  f16* Sc = (f16*)(ws + 160 * MB);        // [160,224) [B][S][S] f16 scores -> P
  f16* Wh = (f16*)(ws + 224 * MB);        // [224,230) [3][D][D]
  float* pm = (float*)(ws + 230 * MB);    // 1 MB [B][NCH][S]
  float* pz = (float*)(ws + 231 * MB);    // 1 MB
  float* mcol = (float*)(ws + 232 * MB);  // 64 KB [B][S]
  float* cscale = mcol + (size_t)B_ * S_; // 64 KB
  float* part = (float*)(ws + 233 * MB);  // 1 MB [256][1024]
  f16* selfatt = Xh;

  k_cvt<<<2048, 256, 0, stream>>>(inp, Xh, M_ * D_ / 4);
  k_cvt<<<512, 256, 0, stream>>>(Wq, Wh, D_ * D_ / 4);
  k_cvt<<<512, 256, 0, stream>>>(Wk, Wh + D_ * D_, D_ * D_ / 4);
  k_cvt<<<512, 256, 0, stream>>>(Wv, Wh + 2 * D_ * D_, D_ * D_ / 4);

  // projections: 256^2 8-phase GEMM (K=1024)
  dim3 gp8(D_ / 256, M_ / 256, 1);
  k_gemm8<true, true><<<gp8, 512, 0, stream>>>(Xh, Wh, Qh, bq, D_, D_, 0, 0, 0);
  k_gemm8<true, true><<<gp8, 512, 0, stream>>>(Xh, Wh + D_ * D_, Kh, bk, D_, D_, 0, 0, 0);
  k_gemm8<true, true><<<gp8, 512, 0, stream>>>(Xh, Wh + 2 * D_ * D_, Vh, bv, D_, D_, 0, 0, 0);

  k_transpose<<<dim3(S_ / 64, D_ / 64, B_), 256, 0, stream>>>(Vh, Vt);

  k_scores<<<dim3(S_ / 128, S_ / 128, B_), 256, 0, stream>>>(Qh, Kh, Sc, pm, pz);
  k_combine<<<dim3(S_ / 256, B_), 256, 0, stream>>>(pm, pz, mcol, cscale);
  k_pexp16<<<2048, 256, 0, stream>>>(Sc, mcol, cscale);

  // PV: selfatt = P * (Vt)^T over all 8 batches, 256^2 8-phase (K=2048)
  k_gemm8<true, false><<<dim3(D_ / 256, S_ / 256, B_), 512, 0, stream>>>(
      Sc, Vt, selfatt, nullptr, S_, D_,
      (long)S_ * S_, (long)D_ * S_, (long)S_ * D_);

  k_ln_pool<<<M_ / 64, 256, 0, stream>>>(selfatt, gamma, beta, part);
  k_final<<<(B_ * D_) / 256, 256, 0, stream>>>(part, out);
}